// Round 16
// baseline (44.699 us; speedup 1.0000x reference)
//
#include <hip/hip_runtime.h>
#include <cfloat>
#include <cstddef>

// Problem constants (fixed by setup_inputs): B=32, n=512, H=768, k=5
#define NB 32
#define NN 512
#define NH 768
#define H4 (NH / 4)        // 192 float4 per encI row
#define ROWS (NB * NN)     // 16384
#define MAXK 8
#define INF_C 3000.0f
#define SELF_D 9000000.0f  // INF*INF self-distance

typedef float f32x4 __attribute__((ext_vector_type(4)));

__device__ __forceinline__ void nt_store4(float4* p, float4 v) {
  f32x4 t; t.x = v.x; t.y = v.y; t.z = v.z; t.w = v.w;
  __builtin_nontemporal_store(t, (f32x4*)p);
}

// ---------------------------------------------------------------------------
// DPP cross-lane moves (VALU pipe). Ctrl codes validated rounds 4/6/7/9/11/12:
//   0xB1 = quad_perm xor1, 0x4E = quad_perm xor2,
//   0x141 = row_half_mirror (xor7), 0x140 = row_mirror (xor15).
// ---------------------------------------------------------------------------
template <int CTRL>
__device__ __forceinline__ int dpp_i(int x) {
  return __builtin_amdgcn_update_dpp(0, x, CTRL, 0xF, 0xF, true);
}
template <int CTRL>
__device__ __forceinline__ float dpp_f(float x) {
  return __int_as_float(dpp_i<CTRL>(__float_as_int(x)));
}

// 64-lane sum: 4 DPP adds -> per-16-group sums, then readlane 0/16/32/48.
__device__ __forceinline__ float wave_sum64(float x) {
  x += dpp_f<0xB1>(x);
  x += dpp_f<0x4E>(x);
  x += dpp_f<0x141>(x);
  x += dpp_f<0x140>(x);
  int xi = __float_as_int(x);
  float a = __int_as_float(__builtin_amdgcn_readlane(xi, 0));
  float b = __int_as_float(__builtin_amdgcn_readlane(xi, 16));
  float c = __int_as_float(__builtin_amdgcn_readlane(xi, 32));
  float d = __int_as_float(__builtin_amdgcn_readlane(xi, 48));
  return (a + b) + (c + d);
}

// lexicographic argmin step on (bv,bj): (bv,bj) <- min((bv,bj),(ov,oj))
#define ARGMIN_COMBINE(ov, oj)                                       \
  do {                                                               \
    float _ov = (ov); int _oj = (oj);                                \
    if (_ov < bv || (_ov == bv && _oj < bj)) { bv = _ov; bj = _oj; } \
  } while (0)

// ---------------------------------------------------------------------------
// Kernel 1: blocks [0,768): direct batch row-sum S4 (block (b,g): 8 float4
//           cols of batch b; 32 row-chunks x 8 cols threads; LDS tree).
//           blocks [768,832): adjusted box centers.  (round 12, proven)
// ---------------------------------------------------------------------------
__global__ __launch_bounds__(256) void prep_kernel(const float* __restrict__ sp,
                                                   const int* __restrict__ mask,
                                                   const float4* __restrict__ e4,
                                                   float2* __restrict__ ctr,
                                                   float4* __restrict__ S4) {
  int bid = blockIdx.x;
  if (bid < 768) {
    int b = bid / 24, g = bid % 24;           // batch, col-group (8 float4)
    int c = threadIdx.x & 7;                  // col within group
    int rc = threadIdx.x >> 3;                // row-chunk (16 rows each)
    const float4* p = e4 + ((size_t)(b * NN + rc * 16)) * H4 + g * 8 + c;
    float ax = 0.f, ay = 0.f, az = 0.f, aw = 0.f;
#pragma unroll
    for (int r = 0; r < 16; ++r) {
      float4 v = p[(size_t)r * H4];
      ax += v.x; ay += v.y; az += v.z; aw += v.w;
    }
    __shared__ float4 red[32][8];             // 4 KB
    red[rc][c] = make_float4(ax, ay, az, aw);
    __syncthreads();
#pragma unroll
    for (int s = 16; s >= 1; s >>= 1) {
      if (rc < s) {
        float4 o = red[rc + s][c];
        float4 a = red[rc][c];
        a.x += o.x; a.y += o.y; a.z += o.z; a.w += o.w;
        red[rc][c] = a;
      }
      __syncthreads();
    }
    if (threadIdx.x < 8) S4[b * H4 + g * 8 + threadIdx.x] = red[0][threadIdx.x];
  } else {
    int t = (bid - 768) * 256 + threadIdx.x;  // [0, ROWS)
    const float* s = sp + (size_t)t * 6;
    float cx = __fmul_rn(__fadd_rn(s[0], s[2]), 0.5f);
    float cy = __fmul_rn(__fadd_rn(s[1], s[3]), 0.5f);
    if (mask[t] == 0) { cx = __fadd_rn(cx, INF_C); cy = __fadd_rn(cy, INF_C); }
    ctr[t] = make_float2(cx, cy);
  }
}

// ---------------------------------------------------------------------------
// Fused body (round 12's online depth-2 pipeline), ctr/mask/S from LDS.
// Weights: selected&valid j get exp(sim_j - M)/Z, all others exp(-M)/Z, with
// M = max(0, max valid sim), Z = (512-m)e^{-M} + sum es. Online accumulation:
//   ctxA = sum_s (es_s - e0) * e_j, rescaled by exp(M_old-M_new) on max growth
//   ctx  = invZ * (e0 * S + ctxA)
// GUARD=false requires k == K exactly.
// ---------------------------------------------------------------------------
template <int K, bool GUARD>
__device__ __forceinline__ void fuse_body(const float2* __restrict__ ctr_s,
                                          const int* __restrict__ mask_s,
                                          const float4* __restrict__ S_s,
                                          const float4* __restrict__ e4,
                                          float4* __restrict__ out4,
                                          const float4 (&ei)[3],
                                          int row, int b, int i, int lane, int k) {
  // --- distances (8 candidates per lane; ctr from LDS) ---
  float2 ci = ctr_s[i];
  float dv[8];
#pragma unroll
  for (int c = 0; c < 8; ++c) {
    int j = c * 64 + lane;
    float2 cj = ctr_s[j];
    float dx = __fadd_rn(ci.x, -cj.x);
    float dy = __fadd_rn(ci.y, -cj.y);
    float d = __fsqrt_rn(__fadd_rn(__fmul_rn(dx, dx), __fmul_rn(dy, dy)));
    dv[c] = (j == i) ? SELF_D : d;
  }

  // --- phase 1: top-k extraction (ties -> smaller index = jax.lax.top_k) ---
  int sel[K];
#pragma unroll
  for (int s = 0; s < K; ++s) {
    sel[s] = 0;
    if (!GUARD || s < k) {                    // wave-uniform
      float bv = FLT_MAX;
      int bj = 1 << 30;
#pragma unroll
      for (int c = 0; c < 8; ++c) {
        int j = c * 64 + lane;
        if (dv[c] < bv) { bv = dv[c]; bj = j; }
      }
      ARGMIN_COMBINE(dpp_f<0xB1>(bv), dpp_i<0xB1>(bj));
      ARGMIN_COMBINE(dpp_f<0x4E>(bv), dpp_i<0x4E>(bj));
      ARGMIN_COMBINE(dpp_f<0x141>(bv), dpp_i<0x141>(bj));
      ARGMIN_COMBINE(dpp_f<0x140>(bv), dpp_i<0x140>(bj));
      int bvi = __float_as_int(bv);
      unsigned long long k0 =
          ((unsigned long long)(unsigned)__builtin_amdgcn_readlane(bvi, 0) << 32) |
          (unsigned)__builtin_amdgcn_readlane(bj, 0);
      unsigned long long k1 =
          ((unsigned long long)(unsigned)__builtin_amdgcn_readlane(bvi, 16) << 32) |
          (unsigned)__builtin_amdgcn_readlane(bj, 16);
      unsigned long long k2 =
          ((unsigned long long)(unsigned)__builtin_amdgcn_readlane(bvi, 32) << 32) |
          (unsigned)__builtin_amdgcn_readlane(bj, 32);
      unsigned long long k3 =
          ((unsigned long long)(unsigned)__builtin_amdgcn_readlane(bvi, 48) << 32) |
          (unsigned)__builtin_amdgcn_readlane(bj, 48);
      unsigned long long kb = k0 < k1 ? k0 : k1;
      unsigned long long kc = k2 < k3 ? k2 : k3;
      kb = kb < kc ? kb : kc;
      int js = (int)(unsigned)kb;             // uniform (SGPR) winner index
      sel[s] = js;
#pragma unroll
      for (int c = 0; c < 8; ++c)
        if (c * 64 + lane == js) dv[c] = FLT_MAX;
    }
  }

  // early: store the ei half (spreads the write drain over the kernel)
  size_t ob = (size_t)row * (2 * H4);
#pragma unroll
  for (int q = 0; q < 3; ++q) nt_store4(out4 + ob + q * 64 + lane, ei[q]);

  // --- phase 2: depth-2 pipelined gather pass with online softmax-context ---
  float M = 0.f, e0 = 1.f, sumE = 0.f;
  int m = 0;
  float4 ctxA[3];
#pragma unroll
  for (int q = 0; q < 3; ++q) ctxA[q] = make_float4(0.f, 0.f, 0.f, 0.f);

  // prologue: issue tile 0 (validity from LDS mask — free broadcast)
  float4 c0v = make_float4(0.f, 0.f, 0.f, 0.f);
  float4 c1v = c0v, c2v = c0v;
  int vcur = 0;
  if (!GUARD || 0 < k) {
    const float4* er = e4 + (size_t)(b * NN + sel[0]) * H4;
    c0v = er[0 * 64 + lane];
    c1v = er[1 * 64 + lane];
    c2v = er[2 * 64 + lane];
    vcur = mask_s[sel[0]];
  }

#pragma unroll
  for (int s = 0; s < K; ++s) {
    if (!GUARD || s < k) {                    // wave-uniform
      // issue next tile's loads BEFORE touching the current tile
      float4 n0 = make_float4(0.f, 0.f, 0.f, 0.f);
      float4 n1 = n0, n2 = n0;
      int vnxt = 0;
      if (s + 1 < K && (!GUARD || s + 1 < k)) {
        const float4* er = e4 + (size_t)(b * NN + sel[s + 1]) * H4;
        n0 = er[0 * 64 + lane];
        n1 = er[1 * 64 + lane];
        n2 = er[2 * 64 + lane];
        vnxt = mask_s[sel[s + 1]];
      }
      // dot with current tile
      float p = 0.f;
      p = fmaf(ei[0].x, c0v.x, p); p = fmaf(ei[0].y, c0v.y, p);
      p = fmaf(ei[0].z, c0v.z, p); p = fmaf(ei[0].w, c0v.w, p);
      p = fmaf(ei[1].x, c1v.x, p); p = fmaf(ei[1].y, c1v.y, p);
      p = fmaf(ei[1].z, c1v.z, p); p = fmaf(ei[1].w, c1v.w, p);
      p = fmaf(ei[2].x, c2v.x, p); p = fmaf(ei[2].y, c2v.y, p);
      p = fmaf(ei[2].z, c2v.z, p); p = fmaf(ei[2].w, c2v.w, p);
      float ds = wave_sum64(p);
      if (vcur) {                             // wave-uniform
        ++m;
        float nm = fmaxf(M, ds);
        float scale = __expf(M - nm);         // 1.0 when max unchanged
        float es = __expf(ds - nm);
        M = nm;
        e0 = __expf(-nm);
        sumE = fmaf(sumE, scale, es);
        float w = es - e0;
        ctxA[0].x = fmaf(ctxA[0].x, scale, w * c0v.x);
        ctxA[0].y = fmaf(ctxA[0].y, scale, w * c0v.y);
        ctxA[0].z = fmaf(ctxA[0].z, scale, w * c0v.z);
        ctxA[0].w = fmaf(ctxA[0].w, scale, w * c0v.w);
        ctxA[1].x = fmaf(ctxA[1].x, scale, w * c1v.x);
        ctxA[1].y = fmaf(ctxA[1].y, scale, w * c1v.y);
        ctxA[1].z = fmaf(ctxA[1].z, scale, w * c1v.z);
        ctxA[1].w = fmaf(ctxA[1].w, scale, w * c1v.w);
        ctxA[2].x = fmaf(ctxA[2].x, scale, w * c2v.x);
        ctxA[2].y = fmaf(ctxA[2].y, scale, w * c2v.y);
        ctxA[2].z = fmaf(ctxA[2].z, scale, w * c2v.z);
        ctxA[2].w = fmaf(ctxA[2].w, scale, w * c2v.w);
      }
      // rotate pipeline
      c0v = n0; c1v = n1; c2v = n2; vcur = vnxt;
    }
  }

  // --- phase 3: finalize (S from LDS — no global wait) + ctx stores ---
  float Z = fmaf((float)(NN - m), e0, sumE);
  float invZ = 1.0f / Z;
#pragma unroll
  for (int q = 0; q < 3; ++q) {
    float4 Sv = S_s[q * 64 + lane];
    float4 cx;
    cx.x = invZ * fmaf(e0, Sv.x, ctxA[q].x);
    cx.y = invZ * fmaf(e0, Sv.y, ctxA[q].y);
    cx.z = invZ * fmaf(e0, Sv.z, ctxA[q].z);
    cx.w = invZ * fmaf(e0, Sv.w, ctxA[q].w);
    nt_store4(out4 + ob + H4 + q * 64 + lane, cx);
  }
}

// ---------------------------------------------------------------------------
// Kernel 2: one wave per output row; chunked XCD swizzle (4096 blocks, 8 XCDs).
// Per-block LDS staging of ctr/mask/S (9 KB).
// __launch_bounds__(256, 8): A/B test — the LDS staging freed the late S/mask
// global loads, so the body should now fit the 64-VGPR / 8-waves-per-SIMD tier.
// If VGPR_Count=32 + scratch signature appears (r10), revert to (256,7).
// ---------------------------------------------------------------------------
__global__ __launch_bounds__(256, 8) void fuse_kernel(const float2* __restrict__ ctr,
                                                      const float4* __restrict__ e4,
                                                      const int* __restrict__ mask,
                                                      const float4* __restrict__ S4,
                                                      const int* __restrict__ kptr,
                                                      float4* __restrict__ out4) {
  __shared__ float2 ctr_s[NN];   // 4 KB
  __shared__ int mask_s[NN];     // 2 KB
  __shared__ float4 S_s[H4];     // 3 KB
  int bid = blockIdx.x;
  int swz = (bid & 7) * (ROWS / 4 / 8) + (bid >> 3);  // bijective: 4096 % 8 == 0
  int wid = threadIdx.x >> 6;
  int lane = threadIdx.x & 63;
  int row = swz * 4 + wid;
  int b = row >> 9;
  int i = row & (NN - 1);

  // issue own-row loads FIRST; latency hides under staging + distances
  const float4* erow = e4 + (size_t)row * H4;
  float4 ei[3];
#pragma unroll
  for (int q = 0; q < 3; ++q) ei[q] = erow[q * 64 + lane];

  // stage per-batch tables (coalesced, one pass per block)
#pragma unroll
  for (int r = threadIdx.x; r < NN; r += 256) {
    ctr_s[r] = ctr[b * NN + r];
    mask_s[r] = mask[b * NN + r];
  }
  if (threadIdx.x < H4) S_s[threadIdx.x] = S4[b * H4 + threadIdx.x];
  __syncthreads();

  int k = *kptr;
  if (k == 5) {
    fuse_body<5, false>(ctr_s, mask_s, S_s, e4, out4, ei, row, b, i, lane, 5);
  } else {
    if (k > MAXK) k = MAXK;
    if (k < 0) k = 0;
    fuse_body<MAXK, true>(ctr_s, mask_s, S_s, e4, out4, ei, row, b, i, lane, k);
  }
}

// ---------------------------------------------------------------------------
extern "C" void kernel_launch(void* const* d_in, const int* in_sizes, int n_in,
                              void* d_out, int out_size, void* d_ws, size_t ws_size,
                              hipStream_t stream) {
  const float* encI = (const float*)d_in[0];
  const int* RoI_mask = (const int*)d_in[1];
  const float* spatials = (const float*)d_in[2];
  const int* kptr = (const int*)d_in[3];

  // ws: ctr (128 KB) @0, S4 (96 KB) @128K  -> 224 KB total
  float2* ctr = (float2*)d_ws;
  float4* S4 = (float4*)((char*)d_ws + (size_t)ROWS * sizeof(float2));

  prep_kernel<<<832, 256, 0, stream>>>(spatials, RoI_mask, (const float4*)encI, ctr, S4);
  fuse_kernel<<<ROWS / 4, 256, 0, stream>>>(ctr, (const float4*)encI, RoI_mask, S4, kptr,
                                            (float4*)d_out);
  (void)in_sizes; (void)n_in; (void)out_size; (void)ws_size;
}

// Round 17
// 43.725 us; speedup vs baseline: 1.0223x; 1.0223x over previous
//
#include <hip/hip_runtime.h>
#include <cfloat>
#include <cstddef>

// Problem constants (fixed by setup_inputs): B=32, n=512, H=768, k=5
#define NB 32
#define NN 512
#define NH 768
#define H4 (NH / 4)        // 192 float4 per encI row
#define ROWS (NB * NN)     // 16384
#define MAXK 8
#define INF_C 3000.0f
#define SELF_D 9000000.0f  // INF*INF self-distance

// ---------------------------------------------------------------------------
// DPP cross-lane moves (VALU pipe). Ctrl codes validated rounds 4/6/7/9/11/12:
//   0xB1 = quad_perm xor1, 0x4E = quad_perm xor2,
//   0x141 = row_half_mirror (xor7), 0x140 = row_mirror (xor15).
// ---------------------------------------------------------------------------
template <int CTRL>
__device__ __forceinline__ int dpp_i(int x) {
  return __builtin_amdgcn_update_dpp(0, x, CTRL, 0xF, 0xF, true);
}
template <int CTRL>
__device__ __forceinline__ float dpp_f(float x) {
  return __int_as_float(dpp_i<CTRL>(__float_as_int(x)));
}

// 64-lane sum: 4 DPP adds -> per-16-group sums, then readlane 0/16/32/48.
__device__ __forceinline__ float wave_sum64(float x) {
  x += dpp_f<0xB1>(x);
  x += dpp_f<0x4E>(x);
  x += dpp_f<0x141>(x);
  x += dpp_f<0x140>(x);
  int xi = __float_as_int(x);
  float a = __int_as_float(__builtin_amdgcn_readlane(xi, 0));
  float b = __int_as_float(__builtin_amdgcn_readlane(xi, 16));
  float c = __int_as_float(__builtin_amdgcn_readlane(xi, 32));
  float d = __int_as_float(__builtin_amdgcn_readlane(xi, 48));
  return (a + b) + (c + d);
}

// lexicographic argmin step on (bv,bj): (bv,bj) <- min((bv,bj),(ov,oj))
#define ARGMIN_COMBINE(ov, oj)                                       \
  do {                                                               \
    float _ov = (ov); int _oj = (oj);                                \
    if (_ov < bv || (_ov == bv && _oj < bj)) { bv = _ov; bj = _oj; } \
  } while (0)

// ---------------------------------------------------------------------------
// Kernel 1: blocks [0,768): direct batch row-sum S4 (block (b,g): 8 float4
//           cols of batch b; 32 row-chunks x 8 cols threads; LDS tree).
//           blocks [768,832): adjusted box centers.  (round 12, proven)
// ---------------------------------------------------------------------------
__global__ __launch_bounds__(256) void prep_kernel(const float* __restrict__ sp,
                                                   const int* __restrict__ mask,
                                                   const float4* __restrict__ e4,
                                                   float2* __restrict__ ctr,
                                                   float4* __restrict__ S4) {
  int bid = blockIdx.x;
  if (bid < 768) {
    int b = bid / 24, g = bid % 24;           // batch, col-group (8 float4)
    int c = threadIdx.x & 7;                  // col within group
    int rc = threadIdx.x >> 3;                // row-chunk (16 rows each)
    const float4* p = e4 + ((size_t)(b * NN + rc * 16)) * H4 + g * 8 + c;
    float ax = 0.f, ay = 0.f, az = 0.f, aw = 0.f;
#pragma unroll
    for (int r = 0; r < 16; ++r) {
      float4 v = p[(size_t)r * H4];
      ax += v.x; ay += v.y; az += v.z; aw += v.w;
    }
    __shared__ float4 red[32][8];             // 4 KB
    red[rc][c] = make_float4(ax, ay, az, aw);
    __syncthreads();
#pragma unroll
    for (int s = 16; s >= 1; s >>= 1) {
      if (rc < s) {
        float4 o = red[rc + s][c];
        float4 a = red[rc][c];
        a.x += o.x; a.y += o.y; a.z += o.z; a.w += o.w;
        red[rc][c] = a;
      }
      __syncthreads();
    }
    if (threadIdx.x < 8) S4[b * H4 + g * 8 + threadIdx.x] = red[0][threadIdx.x];
  } else {
    int t = (bid - 768) * 256 + threadIdx.x;  // [0, ROWS)
    const float* s = sp + (size_t)t * 6;
    float cx = __fmul_rn(__fadd_rn(s[0], s[2]), 0.5f);
    float cy = __fmul_rn(__fadd_rn(s[1], s[3]), 0.5f);
    if (mask[t] == 0) { cx = __fadd_rn(cx, INF_C); cy = __fadd_rn(cy, INF_C); }
    ctr[t] = make_float2(cx, cy);
  }
}

// ---------------------------------------------------------------------------
// Fused body, online form with depth-2 gather pipeline (round 12, proven).
// SINGLE CHANGE vs round 12: plain (L2-routed) stores instead of nontemporal —
// A/B of the store path (fills sustain 7 TB/s via L2; NT bypass suspected
// of throttling the write drain).
// Weights: selected&valid j get exp(sim_j - M)/Z, all others exp(-M)/Z, with
// M = max(0, max valid sim), Z = (512-m)e^{-M} + sum es. Online accumulation:
//   ctxA = sum_s (es_s - e0) * e_j, rescaled by exp(M_old-M_new) on max growth
//   ctx  = invZ * (e0 * S + ctxA)
// GUARD=false requires k == K exactly.
// ---------------------------------------------------------------------------
template <int K, bool GUARD>
__device__ __forceinline__ void fuse_body(const float2* __restrict__ ctr,
                                          const int* __restrict__ mask,
                                          const float4* __restrict__ S4,
                                          const float4* __restrict__ e4,
                                          float4* __restrict__ out4,
                                          int row, int b, int i, int lane, int k) {
  // issue own-row loads FIRST; latency hides under distance/topk compute
  const float4* erow = e4 + (size_t)row * H4;
  float4 ei[3];
#pragma unroll
  for (int q = 0; q < 3; ++q) ei[q] = erow[q * 64 + lane];

  // --- distances (8 candidates per lane) ---
  float2 ci = ctr[b * NN + i];
  float dv[8];
#pragma unroll
  for (int c = 0; c < 8; ++c) {
    int j = c * 64 + lane;
    float2 cj = ctr[b * NN + j];
    float dx = __fadd_rn(ci.x, -cj.x);
    float dy = __fadd_rn(ci.y, -cj.y);
    float d = __fsqrt_rn(__fadd_rn(__fmul_rn(dx, dx), __fmul_rn(dy, dy)));
    dv[c] = (j == i) ? SELF_D : d;
  }

  // --- phase 1: top-k extraction (ties -> smaller index = jax.lax.top_k) ---
  int sel[K];
#pragma unroll
  for (int s = 0; s < K; ++s) {
    sel[s] = 0;
    if (!GUARD || s < k) {                    // wave-uniform
      float bv = FLT_MAX;
      int bj = 1 << 30;
#pragma unroll
      for (int c = 0; c < 8; ++c) {
        int j = c * 64 + lane;
        if (dv[c] < bv) { bv = dv[c]; bj = j; }
      }
      ARGMIN_COMBINE(dpp_f<0xB1>(bv), dpp_i<0xB1>(bj));
      ARGMIN_COMBINE(dpp_f<0x4E>(bv), dpp_i<0x4E>(bj));
      ARGMIN_COMBINE(dpp_f<0x141>(bv), dpp_i<0x141>(bj));
      ARGMIN_COMBINE(dpp_f<0x140>(bv), dpp_i<0x140>(bj));
      int bvi = __float_as_int(bv);
      unsigned long long k0 =
          ((unsigned long long)(unsigned)__builtin_amdgcn_readlane(bvi, 0) << 32) |
          (unsigned)__builtin_amdgcn_readlane(bj, 0);
      unsigned long long k1 =
          ((unsigned long long)(unsigned)__builtin_amdgcn_readlane(bvi, 16) << 32) |
          (unsigned)__builtin_amdgcn_readlane(bj, 16);
      unsigned long long k2 =
          ((unsigned long long)(unsigned)__builtin_amdgcn_readlane(bvi, 32) << 32) |
          (unsigned)__builtin_amdgcn_readlane(bj, 32);
      unsigned long long k3 =
          ((unsigned long long)(unsigned)__builtin_amdgcn_readlane(bvi, 48) << 32) |
          (unsigned)__builtin_amdgcn_readlane(bj, 48);
      unsigned long long kb = k0 < k1 ? k0 : k1;
      unsigned long long kc = k2 < k3 ? k2 : k3;
      kb = kb < kc ? kb : kc;
      int js = (int)(unsigned)kb;             // uniform (SGPR) winner index
      sel[s] = js;
#pragma unroll
      for (int c = 0; c < 8; ++c)
        if (c * 64 + lane == js) dv[c] = FLT_MAX;
    }
  }

  // early: store the ei half (spreads the write drain over the kernel)
  size_t ob = (size_t)row * (2 * H4);
#pragma unroll
  for (int q = 0; q < 3; ++q) out4[ob + q * 64 + lane] = ei[q];

  // --- phase 2: depth-2 pipelined gather pass with online softmax-context ---
  float M = 0.f, e0 = 1.f, sumE = 0.f;
  int m = 0;
  float4 ctxA[3];
#pragma unroll
  for (int q = 0; q < 3; ++q) ctxA[q] = make_float4(0.f, 0.f, 0.f, 0.f);

  // prologue: issue tile 0
  float4 c0v = make_float4(0.f, 0.f, 0.f, 0.f);
  float4 c1v = c0v, c2v = c0v;
  int vcur = 0;
  if (!GUARD || 0 < k) {
    const float4* er = e4 + (size_t)(b * NN + sel[0]) * H4;
    c0v = er[0 * 64 + lane];
    c1v = er[1 * 64 + lane];
    c2v = er[2 * 64 + lane];
    vcur = mask[b * NN + sel[0]];
  }

#pragma unroll
  for (int s = 0; s < K; ++s) {
    if (!GUARD || s < k) {                    // wave-uniform
      // issue next tile's loads BEFORE touching the current tile
      float4 n0 = make_float4(0.f, 0.f, 0.f, 0.f);
      float4 n1 = n0, n2 = n0;
      int vnxt = 0;
      if (s + 1 < K && (!GUARD || s + 1 < k)) {
        const float4* er = e4 + (size_t)(b * NN + sel[s + 1]) * H4;
        n0 = er[0 * 64 + lane];
        n1 = er[1 * 64 + lane];
        n2 = er[2 * 64 + lane];
        vnxt = mask[b * NN + sel[s + 1]];
      }
      // dot with current tile
      float p = 0.f;
      p = fmaf(ei[0].x, c0v.x, p); p = fmaf(ei[0].y, c0v.y, p);
      p = fmaf(ei[0].z, c0v.z, p); p = fmaf(ei[0].w, c0v.w, p);
      p = fmaf(ei[1].x, c1v.x, p); p = fmaf(ei[1].y, c1v.y, p);
      p = fmaf(ei[1].z, c1v.z, p); p = fmaf(ei[1].w, c1v.w, p);
      p = fmaf(ei[2].x, c2v.x, p); p = fmaf(ei[2].y, c2v.y, p);
      p = fmaf(ei[2].z, c2v.z, p); p = fmaf(ei[2].w, c2v.w, p);
      float ds = wave_sum64(p);
      if (vcur) {                             // wave-uniform
        ++m;
        float nm = fmaxf(M, ds);
        float scale = __expf(M - nm);         // 1.0 when max unchanged
        float es = __expf(ds - nm);
        M = nm;
        e0 = __expf(-nm);
        sumE = fmaf(sumE, scale, es);
        float w = es - e0;
        ctxA[0].x = fmaf(ctxA[0].x, scale, w * c0v.x);
        ctxA[0].y = fmaf(ctxA[0].y, scale, w * c0v.y);
        ctxA[0].z = fmaf(ctxA[0].z, scale, w * c0v.z);
        ctxA[0].w = fmaf(ctxA[0].w, scale, w * c0v.w);
        ctxA[1].x = fmaf(ctxA[1].x, scale, w * c1v.x);
        ctxA[1].y = fmaf(ctxA[1].y, scale, w * c1v.y);
        ctxA[1].z = fmaf(ctxA[1].z, scale, w * c1v.z);
        ctxA[1].w = fmaf(ctxA[1].w, scale, w * c1v.w);
        ctxA[2].x = fmaf(ctxA[2].x, scale, w * c2v.x);
        ctxA[2].y = fmaf(ctxA[2].y, scale, w * c2v.y);
        ctxA[2].z = fmaf(ctxA[2].z, scale, w * c2v.z);
        ctxA[2].w = fmaf(ctxA[2].w, scale, w * c2v.w);
      }
      // rotate pipeline
      c0v = n0; c1v = n1; c2v = n2; vcur = vnxt;
    }
  }

  // --- phase 3: finalize (Sv loaded only now) + ctx stores ---
  float Z = fmaf((float)(NN - m), e0, sumE);
  float invZ = 1.0f / Z;
#pragma unroll
  for (int q = 0; q < 3; ++q) {
    float4 Sv = S4[b * H4 + q * 64 + lane];
    float4 cx;
    cx.x = invZ * fmaf(e0, Sv.x, ctxA[q].x);
    cx.y = invZ * fmaf(e0, Sv.y, ctxA[q].y);
    cx.z = invZ * fmaf(e0, Sv.z, ctxA[q].z);
    cx.w = invZ * fmaf(e0, Sv.w, ctxA[q].w);
    out4[ob + H4 + q * 64 + lane] = cx;
  }
}

// ---------------------------------------------------------------------------
// Kernel 2: one wave per output row; chunked XCD swizzle (4096 blocks, 8 XCDs).
// __launch_bounds__(256, 7): proven no-spill tier for this body (round 12).
// ---------------------------------------------------------------------------
__global__ __launch_bounds__(256, 7) void fuse_kernel(const float2* __restrict__ ctr,
                                                      const float4* __restrict__ e4,
                                                      const int* __restrict__ mask,
                                                      const float4* __restrict__ S4,
                                                      const int* __restrict__ kptr,
                                                      float4* __restrict__ out4) {
  int bid = blockIdx.x;
  int swz = (bid & 7) * (ROWS / 4 / 8) + (bid >> 3);  // bijective: 4096 % 8 == 0
  int wid = threadIdx.x >> 6;
  int lane = threadIdx.x & 63;
  int row = swz * 4 + wid;
  int b = row >> 9;
  int i = row & (NN - 1);
  int k = *kptr;
  if (k == 5) {
    fuse_body<5, false>(ctr, mask, S4, e4, out4, row, b, i, lane, 5);
  } else {
    if (k > MAXK) k = MAXK;
    if (k < 0) k = 0;
    fuse_body<MAXK, true>(ctr, mask, S4, e4, out4, row, b, i, lane, k);
  }
}

// ---------------------------------------------------------------------------
extern "C" void kernel_launch(void* const* d_in, const int* in_sizes, int n_in,
                              void* d_out, int out_size, void* d_ws, size_t ws_size,
                              hipStream_t stream) {
  const float* encI = (const float*)d_in[0];
  const int* RoI_mask = (const int*)d_in[1];
  const float* spatials = (const float*)d_in[2];
  const int* kptr = (const int*)d_in[3];

  // ws: ctr (128 KB) @0, S4 (96 KB) @128K  -> 224 KB total
  float2* ctr = (float2*)d_ws;
  float4* S4 = (float4*)((char*)d_ws + (size_t)ROWS * sizeof(float2));

  prep_kernel<<<832, 256, 0, stream>>>(spatials, RoI_mask, (const float4*)encI, ctr, S4);
  fuse_kernel<<<ROWS / 4, 256, 0, stream>>>(ctr, (const float4*)encI, RoI_mask, S4, kptr,
                                            (float4*)d_out);
  (void)in_sizes; (void)n_in; (void)out_size; (void)ws_size;
}

// Round 18
// 40.457 us; speedup vs baseline: 1.1049x; 1.0808x over previous
//
#include <hip/hip_runtime.h>
#include <cfloat>
#include <cstddef>

// Problem constants (fixed by setup_inputs): B=32, n=512, H=768, k=5
#define NB 32
#define NN 512
#define NH 768
#define H4 (NH / 4)        // 192 float4 per encI row
#define ROWS (NB * NN)     // 16384
#define MAXK 8
#define INF_C 3000.0f
#define SELF_D 9000000.0f  // INF*INF self-distance

typedef float f32x4 __attribute__((ext_vector_type(4)));

__device__ __forceinline__ void nt_store4(float4* p, float4 v) {
  f32x4 t; t.x = v.x; t.y = v.y; t.z = v.z; t.w = v.w;
  __builtin_nontemporal_store(t, (f32x4*)p);
}

// ---------------------------------------------------------------------------
// DPP cross-lane moves (VALU pipe). Ctrl codes validated rounds 4/6/7/9/11/12:
//   0xB1 = quad_perm xor1, 0x4E = quad_perm xor2,
//   0x141 = row_half_mirror (xor7), 0x140 = row_mirror (xor15).
// ---------------------------------------------------------------------------
template <int CTRL>
__device__ __forceinline__ int dpp_i(int x) {
  return __builtin_amdgcn_update_dpp(0, x, CTRL, 0xF, 0xF, true);
}
template <int CTRL>
__device__ __forceinline__ float dpp_f(float x) {
  return __int_as_float(dpp_i<CTRL>(__float_as_int(x)));
}

// 64-lane sum: 4 DPP adds -> per-16-group sums, then readlane 0/16/32/48.
__device__ __forceinline__ float wave_sum64(float x) {
  x += dpp_f<0xB1>(x);
  x += dpp_f<0x4E>(x);
  x += dpp_f<0x141>(x);
  x += dpp_f<0x140>(x);
  int xi = __float_as_int(x);
  float a = __int_as_float(__builtin_amdgcn_readlane(xi, 0));
  float b = __int_as_float(__builtin_amdgcn_readlane(xi, 16));
  float c = __int_as_float(__builtin_amdgcn_readlane(xi, 32));
  float d = __int_as_float(__builtin_amdgcn_readlane(xi, 48));
  return (a + b) + (c + d);
}

// lexicographic argmin step on (bv,bj): (bv,bj) <- min((bv,bj),(ov,oj))
#define ARGMIN_COMBINE(ov, oj)                                       \
  do {                                                               \
    float _ov = (ov); int _oj = (oj);                                \
    if (_ov < bv || (_ov == bv && _oj < bj)) { bv = _ov; bj = _oj; } \
  } while (0)

// ---------------------------------------------------------------------------
// Kernel 1: blocks [0,768): direct batch row-sum S4 (block (b,g): 8 float4
//           cols of batch b; 32 row-chunks x 8 cols threads; LDS tree).
//           blocks [768,832): adjusted box centers.  (round 12, proven)
// ---------------------------------------------------------------------------
__global__ __launch_bounds__(256) void prep_kernel(const float* __restrict__ sp,
                                                   const int* __restrict__ mask,
                                                   const float4* __restrict__ e4,
                                                   float2* __restrict__ ctr,
                                                   float4* __restrict__ S4) {
  int bid = blockIdx.x;
  if (bid < 768) {
    int b = bid / 24, g = bid % 24;           // batch, col-group (8 float4)
    int c = threadIdx.x & 7;                  // col within group
    int rc = threadIdx.x >> 3;                // row-chunk (16 rows each)
    const float4* p = e4 + ((size_t)(b * NN + rc * 16)) * H4 + g * 8 + c;
    float ax = 0.f, ay = 0.f, az = 0.f, aw = 0.f;
#pragma unroll
    for (int r = 0; r < 16; ++r) {
      float4 v = p[(size_t)r * H4];
      ax += v.x; ay += v.y; az += v.z; aw += v.w;
    }
    __shared__ float4 red[32][8];             // 4 KB
    red[rc][c] = make_float4(ax, ay, az, aw);
    __syncthreads();
#pragma unroll
    for (int s = 16; s >= 1; s >>= 1) {
      if (rc < s) {
        float4 o = red[rc + s][c];
        float4 a = red[rc][c];
        a.x += o.x; a.y += o.y; a.z += o.z; a.w += o.w;
        red[rc][c] = a;
      }
      __syncthreads();
    }
    if (threadIdx.x < 8) S4[b * H4 + g * 8 + threadIdx.x] = red[0][threadIdx.x];
  } else {
    int t = (bid - 768) * 256 + threadIdx.x;  // [0, ROWS)
    const float* s = sp + (size_t)t * 6;
    float cx = __fmul_rn(__fadd_rn(s[0], s[2]), 0.5f);
    float cy = __fmul_rn(__fadd_rn(s[1], s[3]), 0.5f);
    if (mask[t] == 0) { cx = __fadd_rn(cx, INF_C); cy = __fadd_rn(cy, INF_C); }
    ctr[t] = make_float2(cx, cy);
  }
}

// ---------------------------------------------------------------------------
// Fused body, online form with depth-2 gather pipeline (round 12, proven best).
// Weights: selected&valid j get exp(sim_j - M)/Z, all others exp(-M)/Z, with
// M = max(0, max valid sim), Z = (512-m)e^{-M} + sum es. Online accumulation:
//   ctxA = sum_s (es_s - e0) * e_j, rescaled by exp(M_old-M_new) on max growth
//   ctx  = invZ * (e0 * S + ctxA)
// GUARD=false requires k == K exactly.
// ---------------------------------------------------------------------------
template <int K, bool GUARD>
__device__ __forceinline__ void fuse_body(const float2* __restrict__ ctr,
                                          const int* __restrict__ mask,
                                          const float4* __restrict__ S4,
                                          const float4* __restrict__ e4,
                                          float4* __restrict__ out4,
                                          int row, int b, int i, int lane, int k) {
  // issue own-row loads FIRST; latency hides under distance/topk compute
  const float4* erow = e4 + (size_t)row * H4;
  float4 ei[3];
#pragma unroll
  for (int q = 0; q < 3; ++q) ei[q] = erow[q * 64 + lane];

  // --- distances (8 candidates per lane) ---
  float2 ci = ctr[b * NN + i];
  float dv[8];
#pragma unroll
  for (int c = 0; c < 8; ++c) {
    int j = c * 64 + lane;
    float2 cj = ctr[b * NN + j];
    float dx = __fadd_rn(ci.x, -cj.x);
    float dy = __fadd_rn(ci.y, -cj.y);
    float d = __fsqrt_rn(__fadd_rn(__fmul_rn(dx, dx), __fmul_rn(dy, dy)));
    dv[c] = (j == i) ? SELF_D : d;
  }

  // --- phase 1: top-k extraction (ties -> smaller index = jax.lax.top_k) ---
  int sel[K];
#pragma unroll
  for (int s = 0; s < K; ++s) {
    sel[s] = 0;
    if (!GUARD || s < k) {                    // wave-uniform
      float bv = FLT_MAX;
      int bj = 1 << 30;
#pragma unroll
      for (int c = 0; c < 8; ++c) {
        int j = c * 64 + lane;
        if (dv[c] < bv) { bv = dv[c]; bj = j; }
      }
      ARGMIN_COMBINE(dpp_f<0xB1>(bv), dpp_i<0xB1>(bj));
      ARGMIN_COMBINE(dpp_f<0x4E>(bv), dpp_i<0x4E>(bj));
      ARGMIN_COMBINE(dpp_f<0x141>(bv), dpp_i<0x141>(bj));
      ARGMIN_COMBINE(dpp_f<0x140>(bv), dpp_i<0x140>(bj));
      int bvi = __float_as_int(bv);
      unsigned long long k0 =
          ((unsigned long long)(unsigned)__builtin_amdgcn_readlane(bvi, 0) << 32) |
          (unsigned)__builtin_amdgcn_readlane(bj, 0);
      unsigned long long k1 =
          ((unsigned long long)(unsigned)__builtin_amdgcn_readlane(bvi, 16) << 32) |
          (unsigned)__builtin_amdgcn_readlane(bj, 16);
      unsigned long long k2 =
          ((unsigned long long)(unsigned)__builtin_amdgcn_readlane(bvi, 32) << 32) |
          (unsigned)__builtin_amdgcn_readlane(bj, 32);
      unsigned long long k3 =
          ((unsigned long long)(unsigned)__builtin_amdgcn_readlane(bvi, 48) << 32) |
          (unsigned)__builtin_amdgcn_readlane(bj, 48);
      unsigned long long kb = k0 < k1 ? k0 : k1;
      unsigned long long kc = k2 < k3 ? k2 : k3;
      kb = kb < kc ? kb : kc;
      int js = (int)(unsigned)kb;             // uniform (SGPR) winner index
      sel[s] = js;
#pragma unroll
      for (int c = 0; c < 8; ++c)
        if (c * 64 + lane == js) dv[c] = FLT_MAX;
    }
  }

  // early: store the ei half (spreads the write drain over the kernel)
  size_t ob = (size_t)row * (2 * H4);
#pragma unroll
  for (int q = 0; q < 3; ++q) nt_store4(out4 + ob + q * 64 + lane, ei[q]);

  // --- phase 2: depth-2 pipelined gather pass with online softmax-context ---
  float M = 0.f, e0 = 1.f, sumE = 0.f;
  int m = 0;
  float4 ctxA[3];
#pragma unroll
  for (int q = 0; q < 3; ++q) ctxA[q] = make_float4(0.f, 0.f, 0.f, 0.f);

  // prologue: issue tile 0
  float4 c0v = make_float4(0.f, 0.f, 0.f, 0.f);
  float4 c1v = c0v, c2v = c0v;
  int vcur = 0;
  if (!GUARD || 0 < k) {
    const float4* er = e4 + (size_t)(b * NN + sel[0]) * H4;
    c0v = er[0 * 64 + lane];
    c1v = er[1 * 64 + lane];
    c2v = er[2 * 64 + lane];
    vcur = mask[b * NN + sel[0]];
  }

#pragma unroll
  for (int s = 0; s < K; ++s) {
    if (!GUARD || s < k) {                    // wave-uniform
      // issue next tile's loads BEFORE touching the current tile
      float4 n0 = make_float4(0.f, 0.f, 0.f, 0.f);
      float4 n1 = n0, n2 = n0;
      int vnxt = 0;
      if (s + 1 < K && (!GUARD || s + 1 < k)) {
        const float4* er = e4 + (size_t)(b * NN + sel[s + 1]) * H4;
        n0 = er[0 * 64 + lane];
        n1 = er[1 * 64 + lane];
        n2 = er[2 * 64 + lane];
        vnxt = mask[b * NN + sel[s + 1]];
      }
      // dot with current tile
      float p = 0.f;
      p = fmaf(ei[0].x, c0v.x, p); p = fmaf(ei[0].y, c0v.y, p);
      p = fmaf(ei[0].z, c0v.z, p); p = fmaf(ei[0].w, c0v.w, p);
      p = fmaf(ei[1].x, c1v.x, p); p = fmaf(ei[1].y, c1v.y, p);
      p = fmaf(ei[1].z, c1v.z, p); p = fmaf(ei[1].w, c1v.w, p);
      p = fmaf(ei[2].x, c2v.x, p); p = fmaf(ei[2].y, c2v.y, p);
      p = fmaf(ei[2].z, c2v.z, p); p = fmaf(ei[2].w, c2v.w, p);
      float ds = wave_sum64(p);
      if (vcur) {                             // wave-uniform
        ++m;
        float nm = fmaxf(M, ds);
        float scale = __expf(M - nm);         // 1.0 when max unchanged
        float es = __expf(ds - nm);
        M = nm;
        e0 = __expf(-nm);
        sumE = fmaf(sumE, scale, es);
        float w = es - e0;
        ctxA[0].x = fmaf(ctxA[0].x, scale, w * c0v.x);
        ctxA[0].y = fmaf(ctxA[0].y, scale, w * c0v.y);
        ctxA[0].z = fmaf(ctxA[0].z, scale, w * c0v.z);
        ctxA[0].w = fmaf(ctxA[0].w, scale, w * c0v.w);
        ctxA[1].x = fmaf(ctxA[1].x, scale, w * c1v.x);
        ctxA[1].y = fmaf(ctxA[1].y, scale, w * c1v.y);
        ctxA[1].z = fmaf(ctxA[1].z, scale, w * c1v.z);
        ctxA[1].w = fmaf(ctxA[1].w, scale, w * c1v.w);
        ctxA[2].x = fmaf(ctxA[2].x, scale, w * c2v.x);
        ctxA[2].y = fmaf(ctxA[2].y, scale, w * c2v.y);
        ctxA[2].z = fmaf(ctxA[2].z, scale, w * c2v.z);
        ctxA[2].w = fmaf(ctxA[2].w, scale, w * c2v.w);
      }
      // rotate pipeline
      c0v = n0; c1v = n1; c2v = n2; vcur = vnxt;
    }
  }

  // --- phase 3: finalize (Sv loaded only now) + ctx stores ---
  float Z = fmaf((float)(NN - m), e0, sumE);
  float invZ = 1.0f / Z;
#pragma unroll
  for (int q = 0; q < 3; ++q) {
    float4 Sv = S4[b * H4 + q * 64 + lane];
    float4 cx;
    cx.x = invZ * fmaf(e0, Sv.x, ctxA[q].x);
    cx.y = invZ * fmaf(e0, Sv.y, ctxA[q].y);
    cx.z = invZ * fmaf(e0, Sv.z, ctxA[q].z);
    cx.w = invZ * fmaf(e0, Sv.w, ctxA[q].w);
    nt_store4(out4 + ob + H4 + q * 64 + lane, cx);
  }
}

// ---------------------------------------------------------------------------
// Kernel 2: one wave per output row; chunked XCD swizzle (4096 blocks, 8 XCDs).
// __launch_bounds__(256, 7): cap ~73 VGPR (7 waves/SIMD) — proven no-spill.
// ---------------------------------------------------------------------------
__global__ __launch_bounds__(256, 7) void fuse_kernel(const float2* __restrict__ ctr,
                                                      const float4* __restrict__ e4,
                                                      const int* __restrict__ mask,
                                                      const float4* __restrict__ S4,
                                                      const int* __restrict__ kptr,
                                                      float4* __restrict__ out4) {
  int bid = blockIdx.x;
  int swz = (bid & 7) * (ROWS / 4 / 8) + (bid >> 3);  // bijective: 4096 % 8 == 0
  int wid = threadIdx.x >> 6;
  int lane = threadIdx.x & 63;
  int row = swz * 4 + wid;
  int b = row >> 9;
  int i = row & (NN - 1);
  int k = *kptr;
  if (k == 5) {
    fuse_body<5, false>(ctr, mask, S4, e4, out4, row, b, i, lane, 5);
  } else {
    if (k > MAXK) k = MAXK;
    if (k < 0) k = 0;
    fuse_body<MAXK, true>(ctr, mask, S4, e4, out4, row, b, i, lane, k);
  }
}

// ---------------------------------------------------------------------------
extern "C" void kernel_launch(void* const* d_in, const int* in_sizes, int n_in,
                              void* d_out, int out_size, void* d_ws, size_t ws_size,
                              hipStream_t stream) {
  const float* encI = (const float*)d_in[0];
  const int* RoI_mask = (const int*)d_in[1];
  const float* spatials = (const float*)d_in[2];
  const int* kptr = (const int*)d_in[3];

  // ws: ctr (128 KB) @0, S4 (96 KB) @128K  -> 224 KB total
  float2* ctr = (float2*)d_ws;
  float4* S4 = (float4*)((char*)d_ws + (size_t)ROWS * sizeof(float2));

  prep_kernel<<<832, 256, 0, stream>>>(spatials, RoI_mask, (const float4*)encI, ctr, S4);
  fuse_kernel<<<ROWS / 4, 256, 0, stream>>>(ctr, (const float4*)encI, RoI_mask, S4, kptr,
                                            (float4*)d_out);
  (void)in_sizes; (void)n_in; (void)out_size; (void)ws_size;
}